// Round 2
// baseline (113.276 us; speedup 1.0000x reference)
//
#include <hip/hip_runtime.h>
#include <stdint.h>

typedef unsigned short u16;
typedef unsigned int u32;
typedef __attribute__((ext_vector_type(4))) float f32x4;
typedef __attribute__((ext_vector_type(4))) u16 u16x4;
typedef __attribute__((ext_vector_type(8))) __bf16 bf16x8;

__device__ __forceinline__ u16 f2bf(float f) {
  u32 u = __builtin_bit_cast(u32, f);
  u = (u + 0x7FFFu + ((u >> 16) & 1u)) >> 16;   // RNE
  return (u16)u;
}

__device__ __forceinline__ void gload_lds16(const void* g, void* l) {
  __builtin_amdgcn_global_load_lds(
      (const __attribute__((address_space(1))) void*)(uintptr_t)(g),
      (__attribute__((address_space(3))) void*)(u32)(uintptr_t)(l),
      16, 0, 0);
}

// ---------------- fp32 -> bf16, identity layout ----------------
__global__ void k_cvt(const float* __restrict__ in, u16* __restrict__ out, int n4) {
  int i = blockIdx.x * 256 + threadIdx.x;
  if (i >= n4) return;
  f32x4 v = ((const f32x4*)in)[i];
  u16x4 o = { f2bf(v.x), f2bf(v.y), f2bf(v.z), f2bf(v.w) };
  ((u16x4*)out)[i] = o;
}

// -------- transpose+convert: in [K][N] f32 -> out [N][K] bf16 ----------
__global__ void k_transpose(const float* __restrict__ in, u16* __restrict__ out,
                            int K, int N) {
  __shared__ float tile[32][33];
  int n0 = blockIdx.x * 32, k0 = blockIdx.y * 32;
  int t = threadIdx.x;
  int c = t & 31, r0 = t >> 5;
#pragma unroll
  for (int i = 0; i < 4; ++i)
    tile[r0 + i * 8][c] = in[(size_t)(k0 + r0 + i * 8) * N + n0 + c];
  __syncthreads();
  int on = t >> 3, ok = (t & 7) * 4;
  u16x4 o = { f2bf(tile[ok + 0][on]), f2bf(tile[ok + 1][on]),
              f2bf(tile[ok + 2][on]), f2bf(tile[ok + 3][on]) };
  *(u16x4*)&out[(size_t)(n0 + on) * K + k0 + ok] = o;
}

// ---------------- 128x128 tile MFMA GEMM (m97 structure) ----------------
// C[m][n] = sum_k A[m][k] * Bt[n][k] + bias[n]
// EPI=0: n<1024 -> outq bf16; 1024..2047 -> present K f32 + kbf bf16;
//        2048..3071 -> present V f32 + vtw bf16 (transposed per head)
// EPI=1: outp f32 [M][N]
template <int EPI>
__global__ __launch_bounds__(256) void k_gemm(
    const u16* __restrict__ A, const u16* __restrict__ Bt,
    const float* __restrict__ bias, u16* __restrict__ outq,
    float* __restrict__ outp, u16* __restrict__ kbf, u16* __restrict__ vtw,
    int M, int N, int K) {
  __shared__ u16 a_lds[128 * 64];
  __shared__ u16 b_lds[128 * 64];
  const int t = threadIdx.x;
  const int lane = t & 63, w = t >> 6;
  const int m0 = blockIdx.y * 128, n0 = blockIdx.x * 128;
  const int srow = t >> 3;                     // staging row (+i*32)
  const int scb = (t & 7) * 16;                // staging col byte
  const int ssw = scb ^ ((srow & 7) << 4);     // inverse-swizzled source col
  const size_t pitch = (size_t)K * 2;
  const char* aS = (const char*)A + (size_t)(m0 + srow) * pitch + ssw;
  const char* bS = (const char*)Bt + (size_t)(n0 + srow) * pitch + ssw;
  char* al = (char*)a_lds + t * 16;
  char* bl = (char*)b_lds + t * 16;
  const int wm = (w >> 1) * 64, wn = (w & 1) * 64;
  const int cc = lane & 15, g = lane >> 4;

  f32x4 acc[4][4] = {};

  for (int kt = 0; kt < K; kt += 64) {
    __syncthreads();
#pragma unroll
    for (int i = 0; i < 4; ++i) {
      gload_lds16(aS + (size_t)kt * 2 + (size_t)i * 32 * pitch, al + i * 4096);
      gload_lds16(bS + (size_t)kt * 2 + (size_t)i * 32 * pitch, bl + i * 4096);
    }
    __syncthreads();
#pragma unroll
    for (int kk = 0; kk < 2; ++kk) {
      bf16x8 af[4], bf_[4];
#pragma unroll
      for (int mf = 0; mf < 4; ++mf) {
        int row = wm + mf * 16 + cc;
        af[mf] = *(const bf16x8*)((const char*)a_lds + row * 128 +
                                  ((kk * 64 + g * 16) ^ ((row & 7) << 4)));
      }
#pragma unroll
      for (int nf = 0; nf < 4; ++nf) {
        int row = wn + nf * 16 + cc;
        bf_[nf] = *(const bf16x8*)((const char*)b_lds + row * 128 +
                                   ((kk * 64 + g * 16) ^ ((row & 7) << 4)));
      }
#pragma unroll
      for (int mf = 0; mf < 4; ++mf)
#pragma unroll
        for (int nf = 0; nf < 4; ++nf)
          acc[mf][nf] = __builtin_amdgcn_mfma_f32_16x16x32_bf16(
              af[mf], bf_[nf], acc[mf][nf], 0, 0, 0);
    }
  }

  float bv[4];
#pragma unroll
  for (int nf = 0; nf < 4; ++nf) bv[nf] = bias[n0 + wn + nf * 16 + cc];

#pragma unroll
  for (int mf = 0; mf < 4; ++mf)
#pragma unroll
    for (int nf = 0; nf < 4; ++nf) {
      int n = n0 + wn + nf * 16 + cc;
      int mb = m0 + wm + mf * 16 + g * 4;
      float v[4];
#pragma unroll
      for (int j = 0; j < 4; ++j) v[j] = acc[mf][nf][j] + bv[nf];
      if (EPI == 1) {
#pragma unroll
        for (int j = 0; j < 4; ++j) outp[(size_t)(mb + j) * N + n] = v[j];
      } else if (n < 1024) {
#pragma unroll
        for (int j = 0; j < 4; ++j) outq[(size_t)(mb + j) * 1024 + n] = f2bf(v[j]);
      } else if (n < 2048) {
        int n2 = n - 1024, hh = n2 >> 6, d = n2 & 63;
        int bb = mb >> 11, ss = mb & 2047;
        float* pr = outp + ((((size_t)bb * 2 + 0) * 16 + hh) * 2048 + ss) * 64 + d;
        u16* kr = kbf + (((size_t)bb * 16 + hh) * 2048 + ss) * 64 + d;
#pragma unroll
        for (int j = 0; j < 4; ++j) { pr[(size_t)j * 64] = v[j]; kr[(size_t)j * 64] = f2bf(v[j]); }
      } else {
        int n2 = n - 2048, hh = n2 >> 6, d = n2 & 63;
        int bb = mb >> 11, ss = mb & 2047;
        float* pr = outp + ((((size_t)bb * 2 + 1) * 16 + hh) * 2048 + ss) * 64 + d;
#pragma unroll
        for (int j = 0; j < 4; ++j) pr[(size_t)j * 64] = v[j];
        u16x4 o = { f2bf(v[0]), f2bf(v[1]), f2bf(v[2]), f2bf(v[3]) };
        *(u16x4*)(vtw + (((size_t)bb * 16 + hh) * 64 + d) * 2048 + ss) = o;
      }
    }
}

// ---------------- fused sparse attention (register-direct, no staging) ----
// grid (qb=16, h=16, b=2), 256 threads = 4 independent waves (32 q rows each).
// Operands loaded as MFMA fragments straight from L2-resident bf16 arrays.
__global__ __launch_bounds__(256, 2) void k_attn(
    const u16* __restrict__ qws, const u16* __restrict__ kbf,
    const u16* __restrict__ vtw, u16* __restrict__ hws) {
  const int qb = blockIdx.x, h = blockIdx.y, b = blockIdx.z;
  const int t = threadIdx.x, lane = t & 63, w = t >> 6;
  const int cc = lane & 15, g = lane >> 4;

  __shared__ u16 p_lds[4][32 * 136];   // per-wave P [32 q][136] (128-key chunk)
  __shared__ float rsum[4][32];

  const char* kh = (const char*)kbf + (size_t)(b * 16 + h) * (2048 * 128);
  const char* vh = (const char*)vtw + (size_t)(b * 16 + h) * (64 * 4096);

  // ---- Q fragments from global ----
  bf16x8 qf_[2][2];
  {
    const char* qsrc = (const char*)qws +
        (size_t)(b * 2048 + qb * 128 + w * 32 + cc) * 2048 + h * 128 + g * 16;
#pragma unroll
    for (int qf = 0; qf < 2; ++qf)
#pragma unroll
      for (int kk = 0; kk < 2; ++kk)
        qf_[qf][kk] = *(const bf16x8*)(qsrc + (size_t)qf * 16 * 2048 + kk * 64);
  }

  const int nsum = 8 * qb;                 // visible summary keys
  const int nkf = 8 + ((nsum + 15) >> 4);  // K-fragments with any visible key

  // ---- swapped QK^T: S^T = mfma(K, Q)  (rows=keys, cols=q) ----
  f32x4 s[16][2] = {};
#pragma unroll
  for (int kf = 0; kf < 16; ++kf) {
    if (kf < nkf) {                        // uniform branch; static indexing kept
      int row = (kf < 8) ? (qb * 128 + kf * 16 + cc)
                         : (((kf - 8) * 2 + (cc >> 3)) * 128 + 120 + (cc & 7));
      const char* kr = kh + (size_t)row * 128 + g * 16;
#pragma unroll
      for (int kk = 0; kk < 2; ++kk) {
        bf16x8 kfr = *(const bf16x8*)(kr + kk * 64);
#pragma unroll
        for (int qf = 0; qf < 2; ++qf)
          s[kf][qf] = __builtin_amdgcn_mfma_f32_16x16x32_bf16(kfr, qf_[qf][kk],
                                                              s[kf][qf], 0, 0, 0);
      }
    }
  }

  // ---- mask + softmax (per-lane 64 keys/qf + 4-lane-group shfl reduce) ----
#pragma unroll
  for (int qf = 0; qf < 2; ++qf) {
    int q_local = w * 32 + qf * 16 + cc;
    float mx = -1e30f;
#pragma unroll
    for (int kf = 0; kf < 16; ++kf)
#pragma unroll
      for (int j = 0; j < 4; ++j) {
        int key = kf * 16 + g * 4 + j;
        float v = s[kf][qf][j] * 0.125f;
        bool vis = (key < 128) ? (key <= q_local) : (key - 128 < nsum);
        v = vis ? v : -1e30f;
        s[kf][qf][j] = v;
        mx = fmaxf(mx, v);
      }
    mx = fmaxf(mx, __shfl_xor(mx, 16));
    mx = fmaxf(mx, __shfl_xor(mx, 32));
    float sum = 0.f;
#pragma unroll
    for (int kf = 0; kf < 16; ++kf)
#pragma unroll
      for (int j = 0; j < 4; ++j) {
        float p = exp2f((s[kf][qf][j] - mx) * 1.44269504088896f);
        s[kf][qf][j] = p;
        sum += p;
      }
    sum += __shfl_xor(sum, 16);
    sum += __shfl_xor(sum, 32);
    if (g == 0) rsum[w][qf * 16 + cc] = sum;
  }

  // ---- PV in 2 chunks of 128 keys (per-wave P buffer, no barriers) ----
  f32x4 o_[2][4] = {};
#pragma unroll
  for (int ch = 0; ch < 2; ++ch) {
#pragma unroll
    for (int qf = 0; qf < 2; ++qf)
#pragma unroll
      for (int kf2 = 0; kf2 < 8; ++kf2) {
        int kf = ch * 8 + kf2;
        u16x4 o = { f2bf(s[kf][qf][0]), f2bf(s[kf][qf][1]),
                    f2bf(s[kf][qf][2]), f2bf(s[kf][qf][3]) };
        *(u16x4*)&p_lds[w][(qf * 16 + cc) * 136 + kf2 * 16 + g * 4] = o;
      }
#pragma unroll
    for (int kk = 0; kk < 4; ++kk) {
      bf16x8 pa[2], vb[4];
#pragma unroll
      for (int mf = 0; mf < 2; ++mf)
        pa[mf] = *(const bf16x8*)((const char*)p_lds[w] +
                                  (mf * 16 + cc) * 272 + kk * 64 + g * 16);
#pragma unroll
      for (int nf = 0; nf < 4; ++nf) {
        const char* vrow = vh + (size_t)(nf * 16 + cc) * 4096;
        int cb = (ch == 0) ? (qb * 256 + kk * 64 + g * 16)
                           : (((kk * 4 + g) * 128 + 120) * 2);
        vb[nf] = *(const bf16x8*)(vrow + cb);
      }
#pragma unroll
      for (int mf = 0; mf < 2; ++mf)
#pragma unroll
        for (int nf = 0; nf < 4; ++nf)
          o_[mf][nf] = __builtin_amdgcn_mfma_f32_16x16x32_bf16(pa[mf], vb[nf],
                                                               o_[mf][nf], 0, 0, 0);
    }
  }

  // ---- epilogue: divide by row sum, write merged-head bf16 ----
#pragma unroll
  for (int mf = 0; mf < 2; ++mf)
#pragma unroll
    for (int j = 0; j < 4; ++j) {
      float inv = 1.0f / rsum[w][mf * 16 + g * 4 + j];
      size_t row = (size_t)(b * 2048 + qb * 128 + w * 32 + mf * 16 + g * 4 + j);
#pragma unroll
      for (int nf = 0; nf < 4; ++nf)
        hws[row * 1024 + h * 64 + nf * 16 + cc] = f2bf(o_[mf][nf][j] * inv);
    }
}

extern "C" void kernel_launch(void* const* d_in, const int* in_sizes, int n_in,
                              void* d_out, int out_size, void* d_ws, size_t ws_size,
                              hipStream_t stream) {
  const float* x      = (const float*)d_in[0];  // [2,2048,1024]
  const float* w_attn = (const float*)d_in[1];  // [1024,3072]
  const float* b_attn = (const float*)d_in[2];  // [3072]
  const float* w_proj = (const float*)d_in[3];  // [1024,1024]
  const float* b_proj = (const float*)d_in[4];  // [1024]
  float* h_out   = (float*)d_out;               // 4,194,304 f32
  float* present = (float*)d_out + 4194304;     // [2][2][16][2048][64] f32

  char* ws = (char*)d_ws;
  u16* xbf = (u16*)(ws);                        // 8 MB  [4096][1024] bf16
  u16* qws = (u16*)(ws + (8u << 20));           // 8 MB  [4096][1024] bf16
  u16* wat = (u16*)(ws + (16u << 20));          // 6 MB  [3072][1024] bf16
  u16* wpt = (u16*)(ws + (22u << 20));          // 2 MB  [1024][1024] bf16
  u16* kbf = (u16*)(ws + (24u << 20));          // 8 MB  [2][16][2048][64] bf16
  u16* vtw = (u16*)(ws + (32u << 20));          // 8 MB  [2][16][64][2048] bf16
  u16* hws = xbf;                               // reuse (x dead after QKV GEMM)

  k_cvt<<<4096, 256, 0, stream>>>(x, xbf, 4096 * 1024 / 4);
  k_transpose<<<dim3(96, 32), 256, 0, stream>>>(w_attn, wat, 1024, 3072);
  k_transpose<<<dim3(32, 32), 256, 0, stream>>>(w_proj, wpt, 1024, 1024);
  k_gemm<0><<<dim3(24, 32), 256, 0, stream>>>(xbf, wat, b_attn, qws, present,
                                              kbf, vtw, 4096, 3072, 1024);
  k_attn<<<dim3(16, 16, 2), 256, 0, stream>>>(qws, kbf, vtw, hws);
  k_gemm<1><<<dim3(8, 32), 256, 0, stream>>>(hws, wpt, b_proj, nullptr, h_out,
                                             nullptr, nullptr, 4096, 1024, 1024);
}

// Round 3
// 97.102 us; speedup vs baseline: 1.1666x; 1.1666x over previous
//
#include <hip/hip_runtime.h>
#include <stdint.h>

typedef unsigned short u16;
typedef unsigned int u32;
typedef __attribute__((ext_vector_type(4))) float f32x4;
typedef __attribute__((ext_vector_type(4))) u16 u16x4;
typedef __attribute__((ext_vector_type(8))) __bf16 bf16x8;

__device__ __forceinline__ u16 f2bf(float f) {
  u32 u = __builtin_bit_cast(u32, f);
  u = (u + 0x7FFFu + ((u >> 16) & 1u)) >> 16;   // RNE
  return (u16)u;
}

__device__ __forceinline__ void gload_lds16(const void* g, void* l) {
  __builtin_amdgcn_global_load_lds(
      (const __attribute__((address_space(1))) void*)(uintptr_t)(g),
      (__attribute__((address_space(3))) void*)(u32)(uintptr_t)(l),
      16, 0, 0);
}

// ---- fused prep: x cvt (blocks 0..4095), w_attn^T (4096..7167), w_proj^T ----
__global__ __launch_bounds__(256) void k_prep(
    const float* __restrict__ x, u16* __restrict__ xbf,
    const float* __restrict__ wa, u16* __restrict__ wat,
    const float* __restrict__ wp, u16* __restrict__ wpt) {
  __shared__ float tile[32][33];
  const int bid = blockIdx.x, t = threadIdx.x;
  if (bid < 4096) {
    int i = bid * 256 + t;
    f32x4 v = ((const f32x4*)x)[i];
    u16x4 o = { f2bf(v.x), f2bf(v.y), f2bf(v.z), f2bf(v.w) };
    ((u16x4*)xbf)[i] = o;
    return;
  }
  const float* in;
  u16* out;
  int n0, k0, N;
  if (bid < 4096 + 3072) {
    int idx = bid - 4096;
    in = wa; out = wat; N = 3072;
    n0 = (idx % 96) * 32; k0 = (idx / 96) * 32;
  } else {
    int idx = bid - 7168;
    in = wp; out = wpt; N = 1024;
    n0 = (idx & 31) * 32; k0 = (idx >> 5) * 32;
  }
  int c = t & 31, r0 = t >> 5;
#pragma unroll
  for (int i = 0; i < 4; ++i)
    tile[r0 + i * 8][c] = in[(size_t)(k0 + r0 + i * 8) * N + n0 + c];
  __syncthreads();
  int on = t >> 3, ok = (t & 7) * 4;
  u16x4 o = { f2bf(tile[ok + 0][on]), f2bf(tile[ok + 1][on]),
              f2bf(tile[ok + 2][on]), f2bf(tile[ok + 3][on]) };
  *(u16x4*)&out[(size_t)(n0 + on) * 1024 + k0 + ok] = o;
}

// ---- k_kv: blocks 0..4095 = V^T tiles (f32->bf16), 4096..8191 = K cvt ----
// present [b][kv][h][2048][64] f32 ; vtw [b][h][64][2048] bf16 ; kbf flat K half
__global__ __launch_bounds__(256) void k_kv(const float* __restrict__ present,
                                            u16* __restrict__ kbf,
                                            u16* __restrict__ vtw) {
  __shared__ float tile[32][33];
  const int bid = blockIdx.x, t = threadIdx.x;
  if (bid >= 4096) {
    int i = bid - 4096;
    size_t idx = (size_t)i * 256 + t;           // f32x4 index into K halves
    size_t b = idx >> 19, off = idx & ((1u << 19) - 1);
    f32x4 v = ((const f32x4*)present)[b * (1u << 20) + off];
    u16x4 o = { f2bf(v.x), f2bf(v.y), f2bf(v.z), f2bf(v.w) };
    ((u16x4*)kbf)[idx] = o;
    return;
  }
  int bh = bid >> 7, rem = bid & 127;
  int s0 = (rem >> 1) * 32, d0 = (rem & 1) * 32;
  int b = bh >> 4, h = bh & 15;
  const float* vsrc = present + (((size_t)(b * 2 + 1) * 16 + h) * 2048) * 64;
  u16* vdst = vtw + ((size_t)bh * 64) * 2048;
  int c = t & 31, r0 = t >> 5;
#pragma unroll
  for (int i = 0; i < 4; ++i)
    tile[r0 + i * 8][c] = vsrc[(size_t)(s0 + r0 + i * 8) * 64 + d0 + c];
  __syncthreads();
  int on = t >> 3, ok = (t & 7) * 4;
  u16x4 o = { f2bf(tile[ok + 0][on]), f2bf(tile[ok + 1][on]),
              f2bf(tile[ok + 2][on]), f2bf(tile[ok + 3][on]) };
  *(u16x4*)&vdst[(size_t)(d0 + on) * 2048 + s0 + ok] = o;
}

// ---------------- 128xBN tile MFMA GEMM (m97 structure) ----------------
// C[m][n] = sum_k A[m][k] * Bt[n][k] + bias[n]
// EPI=0 (BN=128): n<1024 -> outq bf16 [M][1024]; else present f32
// EPI=1: outp f32 [M][N]
template <int EPI, int BN>
__global__ __launch_bounds__(256) void k_gemm(
    const u16* __restrict__ A, const u16* __restrict__ Bt,
    const float* __restrict__ bias, u16* __restrict__ outq,
    float* __restrict__ outp, int M, int N, int K) {
  __shared__ u16 a_lds[128 * 64];
  __shared__ u16 b_lds[BN * 64];
  const int t = threadIdx.x;
  const int lane = t & 63, w = t >> 6;
  const int m0 = blockIdx.y * 128, n0 = blockIdx.x * BN;
  const int srow = t >> 3;                     // staging row (+i*32)
  const int scb = (t & 7) * 16;                // staging col byte
  const int ssw = scb ^ ((srow & 7) << 4);     // inverse-swizzled source col
  const size_t pitch = (size_t)K * 2;
  const char* aS = (const char*)A + (size_t)(m0 + srow) * pitch + ssw;
  const char* bS = (const char*)Bt + (size_t)(n0 + srow) * pitch + ssw;
  char* al = (char*)a_lds + t * 16;
  char* bl = (char*)b_lds + t * 16;
  const int wm = (w >> 1) * 64, wn = (w & 1) * (BN / 2);
  const int cc = lane & 15, g = lane >> 4;
  constexpr int NF = BN / 32;

  f32x4 acc[4][NF] = {};

  for (int kt = 0; kt < K; kt += 64) {
    __syncthreads();
#pragma unroll
    for (int i = 0; i < 4; ++i)
      gload_lds16(aS + (size_t)kt * 2 + (size_t)i * 32 * pitch, al + i * 4096);
#pragma unroll
    for (int i = 0; i < BN / 32; ++i)
      gload_lds16(bS + (size_t)kt * 2 + (size_t)i * 32 * pitch, bl + i * 4096);
    __syncthreads();
#pragma unroll
    for (int kk = 0; kk < 2; ++kk) {
      bf16x8 af[4], bf_[NF];
#pragma unroll
      for (int mf = 0; mf < 4; ++mf) {
        int row = wm + mf * 16 + cc;
        af[mf] = *(const bf16x8*)((const char*)a_lds + row * 128 +
                                  ((kk * 64 + g * 16) ^ ((row & 7) << 4)));
      }
#pragma unroll
      for (int nf = 0; nf < NF; ++nf) {
        int row = wn + nf * 16 + cc;
        bf_[nf] = *(const bf16x8*)((const char*)b_lds + row * 128 +
                                   ((kk * 64 + g * 16) ^ ((row & 7) << 4)));
      }
#pragma unroll
      for (int mf = 0; mf < 4; ++mf)
#pragma unroll
        for (int nf = 0; nf < NF; ++nf)
          acc[mf][nf] = __builtin_amdgcn_mfma_f32_16x16x32_bf16(
              af[mf], bf_[nf], acc[mf][nf], 0, 0, 0);
    }
  }

  float bv[NF];
#pragma unroll
  for (int nf = 0; nf < NF; ++nf) bv[nf] = bias[n0 + wn + nf * 16 + cc];

#pragma unroll
  for (int mf = 0; mf < 4; ++mf)
#pragma unroll
    for (int nf = 0; nf < NF; ++nf) {
      int n = n0 + wn + nf * 16 + cc;
      int mb = m0 + wm + mf * 16 + g * 4;
      float v[4];
#pragma unroll
      for (int j = 0; j < 4; ++j) v[j] = acc[mf][nf][j] + bv[nf];
      if (EPI == 1) {
#pragma unroll
        for (int j = 0; j < 4; ++j) outp[(size_t)(mb + j) * N + n] = v[j];
      } else if (n < 1024) {
#pragma unroll
        for (int j = 0; j < 4; ++j) outq[(size_t)(mb + j) * 1024 + n] = f2bf(v[j]);
      } else {
        int n2 = n - 1024;
        int kv = n2 >> 10; n2 &= 1023;
        int hh = n2 >> 6, d = n2 & 63;
        int bb = mb >> 11, ss = mb & 2047;
        float* pr = outp + ((((size_t)bb * 2 + kv) * 16 + hh) * 2048 + ss) * 64 + d;
#pragma unroll
        for (int j = 0; j < 4; ++j) pr[(size_t)j * 64] = v[j];
      }
    }
}

// ---------------- fused sparse attention (register-direct, no staging) ----
// grid (qb=16, h=16, b=2), 256 threads = 4 independent waves (32 q rows each).
__global__ __launch_bounds__(256, 2) void k_attn(
    const u16* __restrict__ qws, const u16* __restrict__ kbf,
    const u16* __restrict__ vtw, u16* __restrict__ hws) {
  const int qb = blockIdx.x, h = blockIdx.y, b = blockIdx.z;
  const int t = threadIdx.x, lane = t & 63, w = t >> 6;
  const int cc = lane & 15, g = lane >> 4;

  __shared__ u16 p_lds[4][32 * 136];   // per-wave P [32 q][136] (128-key chunk)
  __shared__ float rsum[4][32];

  const char* kh = (const char*)kbf + (size_t)(b * 16 + h) * (2048 * 128);
  const char* vh = (const char*)vtw + (size_t)(b * 16 + h) * (64 * 4096);

  // ---- Q fragments from global ----
  bf16x8 qf_[2][2];
  {
    const char* qsrc = (const char*)qws +
        (size_t)(b * 2048 + qb * 128 + w * 32 + cc) * 2048 + h * 128 + g * 16;
#pragma unroll
    for (int qf = 0; qf < 2; ++qf)
#pragma unroll
      for (int kk = 0; kk < 2; ++kk)
        qf_[qf][kk] = *(const bf16x8*)(qsrc + (size_t)qf * 16 * 2048 + kk * 64);
  }

  const int nsum = 8 * qb;                 // visible summary keys
  const int nkf = 8 + ((nsum + 15) >> 4);  // K-fragments with any visible key

  // ---- swapped QK^T: S^T = mfma(K, Q)  (rows=keys, cols=q) ----
  f32x4 s[16][2] = {};
#pragma unroll
  for (int kf = 0; kf < 16; ++kf) {
    if (kf < nkf) {                        // uniform branch; static indexing kept
      int row = (kf < 8) ? (qb * 128 + kf * 16 + cc)
                         : (((kf - 8) * 2 + (cc >> 3)) * 128 + 120 + (cc & 7));
      const char* kr = kh + (size_t)row * 128 + g * 16;
#pragma unroll
      for (int kk = 0; kk < 2; ++kk) {
        bf16x8 kfr = *(const bf16x8*)(kr + kk * 64);
#pragma unroll
        for (int qf = 0; qf < 2; ++qf)
          s[kf][qf] = __builtin_amdgcn_mfma_f32_16x16x32_bf16(kfr, qf_[qf][kk],
                                                              s[kf][qf], 0, 0, 0);
      }
    }
  }

  // ---- mask + softmax (per-lane 64 keys/qf + 4-lane-group shfl reduce) ----
#pragma unroll
  for (int qf = 0; qf < 2; ++qf) {
    int q_local = w * 32 + qf * 16 + cc;
    float mx = -1e30f;
#pragma unroll
    for (int kf = 0; kf < 16; ++kf)
#pragma unroll
      for (int j = 0; j < 4; ++j) {
        int key = kf * 16 + g * 4 + j;
        float v = s[kf][qf][j] * 0.125f;
        bool vis = (key < 128) ? (key <= q_local) : (key - 128 < nsum);
        v = vis ? v : -1e30f;
        s[kf][qf][j] = v;
        mx = fmaxf(mx, v);
      }
    mx = fmaxf(mx, __shfl_xor(mx, 16));
    mx = fmaxf(mx, __shfl_xor(mx, 32));
    float sum = 0.f;
#pragma unroll
    for (int kf = 0; kf < 16; ++kf)
#pragma unroll
      for (int j = 0; j < 4; ++j) {
        float p = exp2f((s[kf][qf][j] - mx) * 1.44269504088896f);
        s[kf][qf][j] = p;
        sum += p;
      }
    sum += __shfl_xor(sum, 16);
    sum += __shfl_xor(sum, 32);
    if (g == 0) rsum[w][qf * 16 + cc] = sum;
  }

  // ---- PV in 2 chunks of 128 keys (per-wave P buffer, no barriers) ----
  f32x4 o_[2][4] = {};
#pragma unroll
  for (int ch = 0; ch < 2; ++ch) {
#pragma unroll
    for (int qf = 0; qf < 2; ++qf)
#pragma unroll
      for (int kf2 = 0; kf2 < 8; ++kf2) {
        int kf = ch * 8 + kf2;
        u16x4 o = { f2bf(s[kf][qf][0]), f2bf(s[kf][qf][1]),
                    f2bf(s[kf][qf][2]), f2bf(s[kf][qf][3]) };
        *(u16x4*)&p_lds[w][(qf * 16 + cc) * 136 + kf2 * 16 + g * 4] = o;
      }
#pragma unroll
    for (int kk = 0; kk < 4; ++kk) {
      bf16x8 pa[2], vb[4];
#pragma unroll
      for (int mf = 0; mf < 2; ++mf)
        pa[mf] = *(const bf16x8*)((const char*)p_lds[w] +
                                  (mf * 16 + cc) * 272 + kk * 64 + g * 16);
#pragma unroll
      for (int nf = 0; nf < 4; ++nf) {
        const char* vrow = vh + (size_t)(nf * 16 + cc) * 4096;
        int cb = (ch == 0) ? (qb * 256 + kk * 64 + g * 16)
                           : (((kk * 4 + g) * 128 + 120) * 2);
        vb[nf] = *(const bf16x8*)(vrow + cb);
      }
#pragma unroll
      for (int mf = 0; mf < 2; ++mf)
#pragma unroll
        for (int nf = 0; nf < 4; ++nf)
          o_[mf][nf] = __builtin_amdgcn_mfma_f32_16x16x32_bf16(pa[mf], vb[nf],
                                                               o_[mf][nf], 0, 0, 0);
    }
  }

  // ---- epilogue: divide by row sum, write merged-head bf16 ----
#pragma unroll
  for (int mf = 0; mf < 2; ++mf)
#pragma unroll
    for (int j = 0; j < 4; ++j) {
      float inv = 1.0f / rsum[w][mf * 16 + g * 4 + j];
      size_t row = (size_t)(b * 2048 + qb * 128 + w * 32 + mf * 16 + g * 4 + j);
#pragma unroll
      for (int nf = 0; nf < 4; ++nf)
        hws[row * 1024 + h * 64 + nf * 16 + cc] = f2bf(o_[mf][nf][j] * inv);
    }
}

extern "C" void kernel_launch(void* const* d_in, const int* in_sizes, int n_in,
                              void* d_out, int out_size, void* d_ws, size_t ws_size,
                              hipStream_t stream) {
  const float* x      = (const float*)d_in[0];  // [2,2048,1024]
  const float* w_attn = (const float*)d_in[1];  // [1024,3072]
  const float* b_attn = (const float*)d_in[2];  // [3072]
  const float* w_proj = (const float*)d_in[3];  // [1024,1024]
  const float* b_proj = (const float*)d_in[4];  // [1024]
  float* h_out   = (float*)d_out;               // 4,194,304 f32
  float* present = (float*)d_out + 4194304;     // [2][2][16][2048][64] f32

  char* ws = (char*)d_ws;
  u16* xbf = (u16*)(ws);                        // 8 MB  [4096][1024] bf16
  u16* qws = (u16*)(ws + (8u << 20));           // 8 MB  [4096][1024] bf16
  u16* wat = (u16*)(ws + (16u << 20));          // 6 MB  [3072][1024] bf16
  u16* wpt = (u16*)(ws + (22u << 20));          // 2 MB  [1024][1024] bf16
  u16* kbf = (u16*)(ws + (24u << 20));          // 8 MB  [2][16][2048][64] bf16
  u16* vtw = (u16*)(ws + (32u << 20));          // 8 MB  [2][16][64][2048] bf16
  u16* hws = xbf;                               // reuse (x dead after QKV GEMM)

  k_prep<<<8192, 256, 0, stream>>>(x, xbf, w_attn, wat, w_proj, wpt);
  k_gemm<0, 128><<<dim3(24, 32), 256, 0, stream>>>(xbf, wat, b_attn, qws,
                                                   present, 4096, 3072, 1024);
  k_kv<<<8192, 256, 0, stream>>>(present, kbf, vtw);
  k_attn<<<dim3(16, 16, 2), 256, 0, stream>>>(qws, kbf, vtw, hws);
  k_gemm<1, 64><<<dim3(16, 32), 256, 0, stream>>>(hws, wpt, b_proj, nullptr,
                                                  h_out, 4096, 1024, 1024);
}

// Round 4
// 91.988 us; speedup vs baseline: 1.2314x; 1.0556x over previous
//
#include <hip/hip_runtime.h>
#include <stdint.h>

typedef unsigned short u16;
typedef unsigned int u32;
typedef __attribute__((ext_vector_type(4))) float f32x4;
typedef __attribute__((ext_vector_type(4))) u16 u16x4;
typedef __attribute__((ext_vector_type(8))) __bf16 bf16x8;

__device__ __forceinline__ u16 f2bf(float f) {
  u32 u = __builtin_bit_cast(u32, f);
  u = (u + 0x7FFFu + ((u >> 16) & 1u)) >> 16;   // RNE
  return (u16)u;
}

__device__ __forceinline__ void gload_lds16(const void* g, void* l) {
  __builtin_amdgcn_global_load_lds(
      (const __attribute__((address_space(1))) void*)(uintptr_t)(g),
      (__attribute__((address_space(3))) void*)(u32)(uintptr_t)(l),
      16, 0, 0);
}

// ---- fused prep: x cvt (blocks 0..4095), w_attn^T (4096..7167), w_proj^T ----
__global__ __launch_bounds__(256) void k_prep(
    const float* __restrict__ x, u16* __restrict__ xbf,
    const float* __restrict__ wa, u16* __restrict__ wat,
    const float* __restrict__ wp, u16* __restrict__ wpt) {
  __shared__ float tile[32][33];
  const int bid = blockIdx.x, t = threadIdx.x;
  if (bid < 4096) {
    int i = bid * 256 + t;
    f32x4 v = ((const f32x4*)x)[i];
    u16x4 o = { f2bf(v.x), f2bf(v.y), f2bf(v.z), f2bf(v.w) };
    ((u16x4*)xbf)[i] = o;
    return;
  }
  const float* in;
  u16* out;
  int n0, k0, N;
  if (bid < 4096 + 3072) {
    int idx = bid - 4096;
    in = wa; out = wat; N = 3072;
    n0 = (idx % 96) * 32; k0 = (idx / 96) * 32;
  } else {
    int idx = bid - 7168;
    in = wp; out = wpt; N = 1024;
    n0 = (idx & 31) * 32; k0 = (idx >> 5) * 32;
  }
  int c = t & 31, r0 = t >> 5;
#pragma unroll
  for (int i = 0; i < 4; ++i)
    tile[r0 + i * 8][c] = in[(size_t)(k0 + r0 + i * 8) * N + n0 + c];
  __syncthreads();
  int on = t >> 3, ok = (t & 7) * 4;
  u16x4 o = { f2bf(tile[ok + 0][on]), f2bf(tile[ok + 1][on]),
              f2bf(tile[ok + 2][on]), f2bf(tile[ok + 3][on]) };
  *(u16x4*)&out[(size_t)(n0 + on) * 1024 + k0 + ok] = o;
}

// ---- k_kv: blocks 0..4095 = V^T tiles (f32->bf16), 4096..8191 = K cvt ----
// present [b][kv][h][2048][64] f32 ; vtw [b][h][64][2048] bf16 ; kbf flat K half
__global__ __launch_bounds__(256) void k_kv(const float* __restrict__ present,
                                            u16* __restrict__ kbf,
                                            u16* __restrict__ vtw) {
  __shared__ float tile[32][33];
  const int bid = blockIdx.x, t = threadIdx.x;
  if (bid >= 4096) {
    int i = bid - 4096;
    size_t idx = (size_t)i * 256 + t;           // f32x4 index into K halves
    size_t b = idx >> 19, off = idx & ((1u << 19) - 1);
    f32x4 v = ((const f32x4*)present)[b * (1u << 20) + off];
    u16x4 o = { f2bf(v.x), f2bf(v.y), f2bf(v.z), f2bf(v.w) };
    ((u16x4*)kbf)[idx] = o;
    return;
  }
  int bh = bid >> 7, rem = bid & 127;
  int s0 = (rem >> 1) * 32, d0 = (rem & 1) * 32;
  int b = bh >> 4, h = bh & 15;
  const float* vsrc = present + (((size_t)(b * 2 + 1) * 16 + h) * 2048) * 64;
  u16* vdst = vtw + ((size_t)bh * 64) * 2048;
  int c = t & 31, r0 = t >> 5;
#pragma unroll
  for (int i = 0; i < 4; ++i)
    tile[r0 + i * 8][c] = vsrc[(size_t)(s0 + r0 + i * 8) * 64 + d0 + c];
  __syncthreads();
  int on = t >> 3, ok = (t & 7) * 4;
  u16x4 o = { f2bf(tile[ok + 0][on]), f2bf(tile[ok + 1][on]),
              f2bf(tile[ok + 2][on]), f2bf(tile[ok + 3][on]) };
  *(u16x4*)&vdst[(size_t)(d0 + on) * 2048 + s0 + ok] = o;
}

// ---------------- 128xBN tile MFMA GEMM (m97 structure) ----------------
template <int EPI, int BN>
__global__ __launch_bounds__(256) void k_gemm(
    const u16* __restrict__ A, const u16* __restrict__ Bt,
    const float* __restrict__ bias, u16* __restrict__ outq,
    float* __restrict__ outp, int M, int N, int K) {
  __shared__ u16 a_lds[128 * 64];
  __shared__ u16 b_lds[BN * 64];
  const int t = threadIdx.x;
  const int lane = t & 63, w = t >> 6;
  const int m0 = blockIdx.y * 128, n0 = blockIdx.x * BN;
  const int srow = t >> 3;
  const int scb = (t & 7) * 16;
  const int ssw = scb ^ ((srow & 7) << 4);
  const size_t pitch = (size_t)K * 2;
  const char* aS = (const char*)A + (size_t)(m0 + srow) * pitch + ssw;
  const char* bS = (const char*)Bt + (size_t)(n0 + srow) * pitch + ssw;
  char* al = (char*)a_lds + t * 16;
  char* bl = (char*)b_lds + t * 16;
  const int wm = (w >> 1) * 64, wn = (w & 1) * (BN / 2);
  const int cc = lane & 15, g = lane >> 4;
  constexpr int NF = BN / 32;

  f32x4 acc[4][NF] = {};

  for (int kt = 0; kt < K; kt += 64) {
    __syncthreads();
#pragma unroll
    for (int i = 0; i < 4; ++i)
      gload_lds16(aS + (size_t)kt * 2 + (size_t)i * 32 * pitch, al + i * 4096);
#pragma unroll
    for (int i = 0; i < BN / 32; ++i)
      gload_lds16(bS + (size_t)kt * 2 + (size_t)i * 32 * pitch, bl + i * 4096);
    __syncthreads();
#pragma unroll
    for (int kk = 0; kk < 2; ++kk) {
      bf16x8 af[4], bf_[NF];
#pragma unroll
      for (int mf = 0; mf < 4; ++mf) {
        int row = wm + mf * 16 + cc;
        af[mf] = *(const bf16x8*)((const char*)a_lds + row * 128 +
                                  ((kk * 64 + g * 16) ^ ((row & 7) << 4)));
      }
#pragma unroll
      for (int nf = 0; nf < NF; ++nf) {
        int row = wn + nf * 16 + cc;
        bf_[nf] = *(const bf16x8*)((const char*)b_lds + row * 128 +
                                   ((kk * 64 + g * 16) ^ ((row & 7) << 4)));
      }
#pragma unroll
      for (int mf = 0; mf < 4; ++mf)
#pragma unroll
        for (int nf = 0; nf < NF; ++nf)
          acc[mf][nf] = __builtin_amdgcn_mfma_f32_16x16x32_bf16(
              af[mf], bf_[nf], acc[mf][nf], 0, 0, 0);
    }
  }

  float bv[NF];
#pragma unroll
  for (int nf = 0; nf < NF; ++nf) bv[nf] = bias[n0 + wn + nf * 16 + cc];

#pragma unroll
  for (int mf = 0; mf < 4; ++mf)
#pragma unroll
    for (int nf = 0; nf < NF; ++nf) {
      int n = n0 + wn + nf * 16 + cc;
      int mb = m0 + wm + mf * 16 + g * 4;
      float v[4];
#pragma unroll
      for (int j = 0; j < 4; ++j) v[j] = acc[mf][nf][j] + bv[nf];
      if (EPI == 1) {
#pragma unroll
        for (int j = 0; j < 4; ++j) outp[(size_t)(mb + j) * N + n] = v[j];
      } else if (n < 1024) {
#pragma unroll
        for (int j = 0; j < 4; ++j) outq[(size_t)(mb + j) * 1024 + n] = f2bf(v[j]);
      } else {
        int n2 = n - 1024;
        int kv = n2 >> 10; n2 &= 1023;
        int hh = n2 >> 6, d = n2 & 63;
        int bb = mb >> 11, ss = mb & 2047;
        float* pr = outp + ((((size_t)bb * 2 + kv) * 16 + hh) * 2048 + ss) * 64 + d;
#pragma unroll
        for (int j = 0; j < 4; ++j) pr[(size_t)j * 64] = v[j];
      }
    }
}

// ---------------- fused sparse attention v3 ----------------
// grid (qb=16, h=16, b=2), 256 threads = 4 waves x 32 q rows.
// K rows (local 128 + summary 128) DMA-staged to swizzled LDS, shared by all
// waves. Branch-free QK over all 256 staged keys; masking handles visibility.
// No max-subtraction (S/8 is O(1)); 4 chunks of 64 keys bound s-liveness.
__global__ __launch_bounds__(256) void k_attn(
    const u16* __restrict__ qws, const u16* __restrict__ kbf,
    const u16* __restrict__ vtw, u16* __restrict__ hws) {
  const int qb = blockIdx.x, h = blockIdx.y, b = blockIdx.z;
  const int t = threadIdx.x, lane = t & 63, w = t >> 6;
  const int cc = lane & 15, g = lane >> 4;

  __shared__ u16 k_lds[256 * 64];      // [256 keys][128 B], XOR-swizzled
  __shared__ u16 p_lds[4][32 * 72];    // per-wave P [32 q][144 B]
  __shared__ float rsum[4][32];

  const char* kh = (const char*)kbf + (size_t)(b * 16 + h) * (2048 * 128);
  const char* vh = (const char*)vtw + (size_t)(b * 16 + h) * (64 * 4096);

  // ---- DMA-stage 256 gathered K rows (pre-swizzled source, linear LDS) ----
  {
    int rr = t >> 3, seg = (t & 7) * 16;
#pragma unroll
    for (int i = 0; i < 8; ++i) {
      int r = i * 32 + rr;
      int i2 = r - 128;
      int gr = (r < 128) ? (qb * 128 + r) : ((i2 >> 3) * 128 + 120 + (i2 & 7));
      gload_lds16(kh + (size_t)gr * 128 + (seg ^ ((r & 7) << 4)),
                  (char*)k_lds + i * 4096 + t * 16);
    }
  }

  // ---- Q fragments from global (overlap with DMA drain) ----
  bf16x8 qf_[2][2];
  {
    const char* qsrc = (const char*)qws +
        (size_t)(b * 2048 + qb * 128 + w * 32 + cc) * 2048 + h * 128 + g * 16;
#pragma unroll
    for (int qf = 0; qf < 2; ++qf)
#pragma unroll
      for (int kk = 0; kk < 2; ++kk)
        qf_[qf][kk] = *(const bf16x8*)(qsrc + (size_t)qf * 16 * 2048 + kk * 64);
  }
  __syncthreads();

  const int nsum = 8 * qb;             // visible summary keys
  f32x4 o_[2][4] = {};
  float lsum[2] = { 0.f, 0.f };

#pragma unroll 2
  for (int ch = 0; ch < 4; ++ch) {
    // ---- QK^T for 64 keys (swapped: rows=keys, cols=q) ----
    f32x4 s[4][2] = {};
#pragma unroll
    for (int kf2 = 0; kf2 < 4; ++kf2) {
      int row = ch * 64 + kf2 * 16 + cc;
      const char* kr = (const char*)k_lds + row * 128;
#pragma unroll
      for (int kk = 0; kk < 2; ++kk) {
        bf16x8 kfr = *(const bf16x8*)(kr + ((kk * 64 + g * 16) ^ ((cc & 7) << 4)));
#pragma unroll
        for (int qf = 0; qf < 2; ++qf)
          s[kf2][qf] = __builtin_amdgcn_mfma_f32_16x16x32_bf16(
              kfr, qf_[qf][kk], s[kf2][qf], 0, 0, 0);
      }
    }
    // ---- mask + exp (no max-sub) + partial sum + P pack ----
#pragma unroll
    for (int qf = 0; qf < 2; ++qf) {
      int q_local = w * 32 + qf * 16 + cc;
#pragma unroll
      for (int kf2 = 0; kf2 < 4; ++kf2) {
#pragma unroll
        for (int j = 0; j < 4; ++j) {
          int key = ch * 64 + kf2 * 16 + g * 4 + j;
          bool vis = (key < 128) ? (key <= q_local) : (key - 128 < nsum);
          float p = vis ? exp2f(s[kf2][qf][j] * 0.180336884f) : 0.f;
          s[kf2][qf][j] = p;
          lsum[qf] += p;
        }
        u16x4 pw = { f2bf(s[kf2][qf][0]), f2bf(s[kf2][qf][1]),
                     f2bf(s[kf2][qf][2]), f2bf(s[kf2][qf][3]) };
        *(u16x4*)&p_lds[w][(qf * 16 + cc) * 72 + kf2 * 16 + g * 4] = pw;
      }
    }
    // ---- PV for this 64-key chunk ----
#pragma unroll
    for (int kk = 0; kk < 2; ++kk) {
      bf16x8 pa[2], vb[4];
#pragma unroll
      for (int mf = 0; mf < 2; ++mf)
        pa[mf] = *(const bf16x8*)((const char*)p_lds[w] +
                                  (mf * 16 + cc) * 144 + kk * 64 + g * 16);
      int cb = (ch < 2) ? (qb * 256 + ch * 128 + kk * 64 + g * 16)
                        : (((ch - 2) * 8 + kk * 4 + g) * 256 + 240);
#pragma unroll
      for (int nf = 0; nf < 4; ++nf)
        vb[nf] = *(const bf16x8*)(vh + (size_t)(nf * 16 + cc) * 4096 + cb);
#pragma unroll
      for (int mf = 0; mf < 2; ++mf)
#pragma unroll
        for (int nf = 0; nf < 4; ++nf)
          o_[mf][nf] = __builtin_amdgcn_mfma_f32_16x16x32_bf16(pa[mf], vb[nf],
                                                               o_[mf][nf], 0, 0, 0);
    }
  }

  // ---- row-sum reduce + epilogue ----
#pragma unroll
  for (int qf = 0; qf < 2; ++qf) {
    float sum = lsum[qf];
    sum += __shfl_xor(sum, 16);
    sum += __shfl_xor(sum, 32);
    if (g == 0) rsum[w][qf * 16 + cc] = sum;
  }
#pragma unroll
  for (int mf = 0; mf < 2; ++mf)
#pragma unroll
    for (int j = 0; j < 4; ++j) {
      float inv = 1.0f / rsum[w][mf * 16 + g * 4 + j];
      size_t row = (size_t)(b * 2048 + qb * 128 + w * 32 + mf * 16 + g * 4 + j);
#pragma unroll
      for (int nf = 0; nf < 4; ++nf)
        hws[row * 1024 + h * 64 + nf * 16 + cc] = f2bf(o_[mf][nf][j] * inv);
    }
}

extern "C" void kernel_launch(void* const* d_in, const int* in_sizes, int n_in,
                              void* d_out, int out_size, void* d_ws, size_t ws_size,
                              hipStream_t stream) {
  const float* x      = (const float*)d_in[0];  // [2,2048,1024]
  const float* w_attn = (const float*)d_in[1];  // [1024,3072]
  const float* b_attn = (const float*)d_in[2];  // [3072]
  const float* w_proj = (const float*)d_in[3];  // [1024,1024]
  const float* b_proj = (const float*)d_in[4];  // [1024]
  float* h_out   = (float*)d_out;               // 4,194,304 f32
  float* present = (float*)d_out + 4194304;     // [2][2][16][2048][64] f32

  char* ws = (char*)d_ws;
  u16* xbf = (u16*)(ws);                        // 8 MB  [4096][1024] bf16
  u16* qws = (u16*)(ws + (8u << 20));           // 8 MB  [4096][1024] bf16
  u16* wat = (u16*)(ws + (16u << 20));          // 6 MB  [3072][1024] bf16
  u16* wpt = (u16*)(ws + (22u << 20));          // 2 MB  [1024][1024] bf16
  u16* kbf = (u16*)(ws + (24u << 20));          // 8 MB  [2][16][2048][64] bf16
  u16* vtw = (u16*)(ws + (32u << 20));          // 8 MB  [2][16][64][2048] bf16
  u16* hws = xbf;                               // reuse (x dead after QKV GEMM)

  k_prep<<<8192, 256, 0, stream>>>(x, xbf, w_attn, wat, w_proj, wpt);
  k_gemm<0, 128><<<dim3(24, 32), 256, 0, stream>>>(xbf, wat, b_attn, qws,
                                                   present, 4096, 3072, 1024);
  k_kv<<<8192, 256, 0, stream>>>(present, kbf, vtw);
  k_attn<<<dim3(16, 16, 2), 256, 0, stream>>>(qws, kbf, vtw, hws);
  k_gemm<1, 64><<<dim3(16, 32), 256, 0, stream>>>(hws, wpt, b_proj, nullptr,
                                                  h_out, 4096, 1024, 1024);
}